// Round 5
// baseline (32.669 us; speedup 1.0000x reference)
//
#include <hip/hip_runtime.h>
#include <math.h>

#define NCOL 8192
#define BT   512
#define EPT  16

// exact double constants
#define MZM_LOSS_D 0.8912509381337456   // 10^-0.05
#define YB_LOSS_D  0.9332543007969910   // 10^-0.03
#define MRR_LOSS_D 0.8912509381337456   // 10^-0.05

__global__ __launch_bounds__(BT, 6)
void odp_main(const float* __restrict__ x, const float* __restrict__ w,
              const float* __restrict__ ntp, const float* __restrict__ nsp,
              const float* __restrict__ ntn, const float* __restrict__ nsn,
              float* __restrict__ out)
{
    __shared__ float  redX[8];    // wave max|x|
    __shared__ float  redW[8];    // wave max|w|
    __shared__ float  redT[8];    // wave T (f32)
    __shared__ double redD[8];    // wave D (f64)
    __shared__ double corrd[4];   // cD(t0), cT(t0), cD(tLast), cT(tLast)

    const int t    = threadIdx.x;
    const int lane = t & 63;
    const int wid  = t >> 6;
    const int b    = blockIdx.x;

    const float v_ntp = ntp[b], v_nsp = nsp[b], v_ntn = ntn[b], v_nsn = nsn[b];

    const float*  __restrict__ xrow = x + (size_t)b * NCOL;
    const float4* __restrict__ xr4  = (const float4*)xrow;
    const float4* __restrict__ w4   = (const float4*)w;

    // ---- phase 1: stream x only (own 16 + 4 halo), reduce max|x| ----
    float xf[EPT];
    const int hL = (t > 0)      ? (t * EPT - 2)   : 0;          // 8B-aligned
    const int hR = (t < BT - 1) ? (t * EPT + EPT) : (NCOL - 2); // 8B-aligned
    const float2 hxL = *(const float2*)(xrow + hL);
    const float2 hxR = *(const float2*)(xrow + hR);

    float mx = 0.f;
#pragma unroll
    for (int j = 0; j < 4; ++j) {
        const float4 xv = xr4[t * 4 + j];
        xf[4*j+0]=xv.x; xf[4*j+1]=xv.y; xf[4*j+2]=xv.z; xf[4*j+3]=xv.w;
        mx = fmaxf(mx, fmaxf(fmaxf(fabsf(xv.x), fabsf(xv.y)),
                             fmaxf(fabsf(xv.z), fabsf(xv.w))));
    }
#pragma unroll
    for (int off = 32; off; off >>= 1)
        mx = fmaxf(mx, __shfl_down(mx, off));
    if (lane == 0) redX[wid] = mx;
    __syncthreads();

    float inorm = redX[0];
#pragma unroll
    for (int i = 1; i < 8; ++i) inorm = fmaxf(inorm, redX[i]);
    inorm = (inorm <= 1e-9f) ? 1.f : inorm;

    // correctly-rounded f32 reciprocal (via f64); Markstein => exact f32 div
    const double inv_d = 1.0 / (double)inorm;
    const float  y     = (float)inv_d;

    // ---- phase 2: w loads (L2-hot), quantize, conv, accumulate ----
    float wf[EPT];
    float mw = 0.f;
#pragma unroll
    for (int j = 0; j < 4; ++j) {
        const float4 wv = w4[t * 4 + j];
        wf[4*j+0]=wv.x; wf[4*j+1]=wv.y; wf[4*j+2]=wv.z; wf[4*j+3]=wv.w;
        mw = fmaxf(mw, fmaxf(fmaxf(fabsf(wv.x), fabsf(wv.y)),
                             fmaxf(fabsf(wv.z), fabsf(wv.w))));
    }

    float Q[EPT + 4];
#pragma unroll
    for (int c = 0; c < EPT; ++c) {
        const float a  = fabsf(xf[c]);
        const float q0 = a * y;
        const float r  = fmaf(-inorm, q0, a);
        Q[c + 2] = rintf(fmaf(r, y, q0) * 255.f);
    }
    {
        const float aL0 = fabsf(hxL.x), aL1 = fabsf(hxL.y);
        const float aR0 = fabsf(hxR.x), aR1 = fabsf(hxR.y);
        float q0, r;
        q0 = aL0 * y; r = fmaf(-inorm, q0, aL0); Q[0]  = rintf(fmaf(r, y, q0) * 255.f);
        q0 = aL1 * y; r = fmaf(-inorm, q0, aL1); Q[1]  = rintf(fmaf(r, y, q0) * 255.f);
        q0 = aR0 * y; r = fmaf(-inorm, q0, aR0); Q[18] = rintf(fmaf(r, y, q0) * 255.f);
        q0 = aR1 * y; r = fmaf(-inorm, q0, aR1); Q[19] = rintf(fmaf(r, y, q0) * 255.f);
        if (t == 0)      { Q[0]  = 0.f; Q[1]  = 0.f; }   // conv 'SAME' zero pad
        if (t == BT - 1) { Q[18] = 0.f; Q[19] = 0.f; }
    }

    float Dv[4] = {0.f,0.f,0.f,0.f}, Tv[4] = {0.f,0.f,0.f,0.f};
    double cD = 0.0, cT = 0.0;
    const double DE0 = -((double)0.01f + (double)0.0025f);  // i = 0, N-1
    const double DE1 = -((double)0.0025f);                  // i = 1, N-2

#pragma unroll
    for (int c = 0; c < EPT; ++c) {
        const float s1 = Q[c + 1] + Q[c + 3];
        const float s2 = Q[c]     + Q[c + 4];
        float conv = fmaf(0.01f, s1, Q[c + 2]);
        conv = fmaf(0.0025f, s2, conv);
        const float sel = (xf[c] > 0.f) ? wf[c] : -wf[c];   // cmp + cndmask(-mod)
        Dv[c & 3] = fmaf(conv, sel,        Dv[c & 3]);
        Tv[c & 3] = fmaf(conv, fabsf(sel), Tv[c & 3]);      // |sel| = |w|, free mod
    }
    if (t == 0) {
#pragma unroll
        for (int c = 0; c < 2; ++c) {
            const float s1 = Q[c + 1] + Q[c + 3];
            const float s2 = Q[c]     + Q[c + 4];
            float conv = fmaf(0.01f, s1, Q[c + 2]);
            conv = fmaf(0.0025f, s2, conv);
            const float sel = (xf[c] > 0.f) ? wf[c] : -wf[c];
            const double de = (c == 0) ? DE0 : DE1;
            cD += de * (double)(conv * sel);
            cT += de * (double)(conv * fabsf(sel));
        }
    }
    if (t == BT - 1) {
#pragma unroll
        for (int c = EPT - 2; c < EPT; ++c) {
            const float s1 = Q[c + 1] + Q[c + 3];
            const float s2 = Q[c]     + Q[c + 4];
            float conv = fmaf(0.01f, s1, Q[c + 2]);
            conv = fmaf(0.0025f, s2, conv);
            const float sel = (xf[c] > 0.f) ? wf[c] : -wf[c];
            const double de = (c == EPT - 1) ? DE0 : DE1;
            cD += de * (double)(conv * sel);
            cT += de * (double)(conv * fabsf(sel));
        }
    }

    double accD = ((double)Dv[0] + (double)Dv[1]) + ((double)Dv[2] + (double)Dv[3]);
    float  accT = (Tv[0] + Tv[1]) + (Tv[2] + Tv[3]);

    // ---- single end reduce: D (f64), T (f32), max|w| (f32) ----
#pragma unroll
    for (int off = 32; off; off >>= 1) {
        accD += __shfl_down(accD, off);
        accT += __shfl_down(accT, off);
        mw    = fmaxf(mw, __shfl_down(mw, off));
    }
    if (lane == 0)   { redD[wid] = accD; redT[wid] = accT; redW[wid] = mw; }
    if (t == 0)      { corrd[0] = cD; corrd[1] = cT; }
    if (t == BT - 1) { corrd[2] = cD; corrd[3] = cT; }
    __syncthreads();

    if (t == 0) {
        double D = 0.0, T = 0.0;
        float wnorm = redW[0];
#pragma unroll
        for (int i = 0; i < 8; ++i) {
            D += redD[i]; T += (double)redT[i];
            wnorm = fmaxf(wnorm, redW[i]);
        }
        wnorm = (wnorm <= 1e-9f) ? 1.f : wnorm;

        const double E_MID = 1.0 + 2.0 * (double)0.01f + 2.0 * (double)0.0025f;
        D = D * E_MID + (corrd[0] + corrd[2]);
        T = T * E_MID + (corrd[1] + corrd[3]);

        const double Kd = (10.0 / 255.0) * (YB_LOSS_D * MZM_LOSS_D) / (double)wnorm;
        const double ps = (T + D) * 0.5 * Kd * MRR_LOSS_D;
        const double ns = (T - D) * 0.5 * Kd * MRR_LOSS_D;

        const float thermal_f = 3.3135576e-12f;   // f32(4*kB*T*Hz/R)
        const float shot_f    = 3.204353268e-9f;  // f32(2*qE*Hz)

        double tp_ = ps + 1e-12 + (double)(v_ntp * thermal_f);
        tp_ *= (double)(1.0f + v_nsp * shot_f);   // == *1.0 in f32, faithful
        double tn_ = ns + 1e-12 + (double)(v_ntn * thermal_f);
        tn_ *= (double)(1.0f + v_nsn * shot_f);

        const double cur = tp_ - tn_;
        double v = fabs(cur * 100.0);
        v = fmin(v, 1.0);
        const double va  = rint(v * 255.0) * (1.0 / 255.0);
        const double sgn = (cur >= 0.0) ? 1.0 : -1.0;
        const double scale = (double)wnorm /
            (10.0 * 100.0 * MRR_LOSS_D * YB_LOSS_D * MZM_LOSS_D);
        out[b] = (float)(va * sgn * scale * (double)inorm);
    }
}

extern "C" void kernel_launch(void* const* d_in, const int* in_sizes, int n_in,
                              void* d_out, int out_size, void* d_ws, size_t ws_size,
                              hipStream_t stream) {
    const float* x   = (const float*)d_in[0];
    const float* w   = (const float*)d_in[1];
    const float* ntp = (const float*)d_in[2];
    const float* nsp = (const float*)d_in[3];
    const float* ntn = (const float*)d_in[4];
    const float* nsn = (const float*)d_in[5];
    float* out = (float*)d_out;
    odp_main<<<dim3(out_size), dim3(BT), 0, stream>>>(x, w, ntp, nsp, ntn, nsn, out);
}

// Round 6
// 32.341 us; speedup vs baseline: 1.0102x; 1.0102x over previous
//
#include <hip/hip_runtime.h>
#include <math.h>

#define NCOL 8192
#define BT   512
#define EPT  16
#define ROWS 8

// exact double constants
#define MZM_LOSS_D 0.8912509381337456   // 10^-0.05
#define YB_LOSS_D  0.9332543007969910   // 10^-0.03
#define MRR_LOSS_D 0.8912509381337456   // 10^-0.05

// load one row's 16 elements + 2+2 halo into registers (global -> VGPR)
#define LOADX(XV, HL, HR, ROWIDX) do {                                        \
    const float* xr_ = x + (size_t)(ROWIDX) * NCOL;                           \
    const float4* xr4_ = (const float4*)xr_;                                  \
    _Pragma("unroll")                                                         \
    for (int j = 0; j < 4; ++j) {                                             \
        const float4 xv_ = xr4_[t * 4 + j];                                   \
        XV[4*j+0]=xv_.x; XV[4*j+1]=xv_.y; XV[4*j+2]=xv_.z; XV[4*j+3]=xv_.w;   \
    }                                                                         \
    HL = *(const float2*)(xr_ + ((t > 0)      ? (t*EPT - 2)   : 0));          \
    HR = *(const float2*)(xr_ + ((t < BT - 1) ? (t*EPT + EPT) : (NCOL - 2))); \
} while (0)

#define ROW_BODY(R, XC, HLC, HRC, PREFETCH) do {                              \
    const int row_ = r0 + (R);                                                \
    const float vntp_ = ntp[row_], vnsp_ = nsp[row_];                         \
    const float vntn_ = ntn[row_], vnsn_ = nsn[row_];                         \
    PREFETCH;                                                                 \
    float mx_ = 0.f;                                                          \
    _Pragma("unroll")                                                         \
    for (int c = 0; c < EPT; ++c) mx_ = fmaxf(mx_, fabsf(XC[c]));             \
    _Pragma("unroll")                                                         \
    for (int off = 32; off; off >>= 1) mx_ = fmaxf(mx_, __shfl_down(mx_, off));\
    if (lane == 0) redX[R][wid] = mx_;                                        \
    if ((R) == 0 && lane == 0) redW[wid] = mw;                                \
    asm volatile("s_waitcnt lgkmcnt(0)" ::: "memory");                        \
    __builtin_amdgcn_s_barrier();                                             \
    float inorm_ = redX[R][0];                                                \
    _Pragma("unroll")                                                         \
    for (int i = 1; i < 8; ++i) inorm_ = fmaxf(inorm_, redX[R][i]);           \
    inorm_ = (inorm_ <= 1e-9f) ? 1.f : inorm_;                                \
    if ((R) == 0) {                                                           \
        float wn_ = redW[0];                                                  \
        _Pragma("unroll")                                                     \
        for (int i = 1; i < 8; ++i) wn_ = fmaxf(wn_, redW[i]);                \
        wnorm = (wn_ <= 1e-9f) ? 1.f : wn_;                                   \
    }                                                                         \
    const double invd_ = 1.0 / (double)inorm_;                                \
    const float  y_    = (float)invd_;                                        \
    float Q[EPT + 4];                                                         \
    _Pragma("unroll")                                                         \
    for (int c = 0; c < EPT; ++c) {                                           \
        const float a_  = fabsf(XC[c]);                                       \
        const float q0_ = a_ * y_;                                            \
        const float r_  = fmaf(-inorm_, q0_, a_);                             \
        Q[c + 2] = rintf(fmaf(r_, y_, q0_) * 255.f);                          \
    }                                                                         \
    {                                                                         \
        const float aL0_=fabsf(HLC.x), aL1_=fabsf(HLC.y);                     \
        const float aR0_=fabsf(HRC.x), aR1_=fabsf(HRC.y);                     \
        float q0_, r_;                                                        \
        q0_=aL0_*y_; r_=fmaf(-inorm_,q0_,aL0_); Q[0] =rintf(fmaf(r_,y_,q0_)*255.f);\
        q0_=aL1_*y_; r_=fmaf(-inorm_,q0_,aL1_); Q[1] =rintf(fmaf(r_,y_,q0_)*255.f);\
        q0_=aR0_*y_; r_=fmaf(-inorm_,q0_,aR0_); Q[18]=rintf(fmaf(r_,y_,q0_)*255.f);\
        q0_=aR1_*y_; r_=fmaf(-inorm_,q0_,aR1_); Q[19]=rintf(fmaf(r_,y_,q0_)*255.f);\
        if (t == 0)      { Q[0]  = 0.f; Q[1]  = 0.f; }                        \
        if (t == BT - 1) { Q[18] = 0.f; Q[19] = 0.f; }                        \
    }                                                                         \
    float Dv_[4] = {0.f,0.f,0.f,0.f}, Tv_[4] = {0.f,0.f,0.f,0.f};             \
    double cD_ = 0.0, cT_ = 0.0;                                              \
    _Pragma("unroll")                                                         \
    for (int c = 0; c < EPT; ++c) {                                           \
        const float s1_ = Q[c + 1] + Q[c + 3];                                \
        const float s2_ = Q[c]     + Q[c + 4];                                \
        float cv_ = fmaf(0.01f, s1_, Q[c + 2]);                               \
        cv_ = fmaf(0.0025f, s2_, cv_);                                        \
        const float sel_ = (XC[c] > 0.f) ? wf[c] : -wf[c];                    \
        Dv_[c & 3] = fmaf(cv_, sel_,        Dv_[c & 3]);                      \
        Tv_[c & 3] = fmaf(cv_, fabsf(sel_), Tv_[c & 3]);                      \
    }                                                                         \
    if (t == 0) {                                                             \
        _Pragma("unroll")                                                     \
        for (int c = 0; c < 2; ++c) {                                         \
            const float s1_ = Q[c + 1] + Q[c + 3];                            \
            const float s2_ = Q[c]     + Q[c + 4];                            \
            float cv_ = fmaf(0.01f, s1_, Q[c + 2]);                           \
            cv_ = fmaf(0.0025f, s2_, cv_);                                    \
            const float sel_ = (XC[c] > 0.f) ? wf[c] : -wf[c];                \
            const double de_ = (c == 0) ? DE0 : DE1;                          \
            cD_ += de_ * (double)(cv_ * sel_);                                \
            cT_ += de_ * (double)(cv_ * fabsf(sel_));                         \
        }                                                                     \
    }                                                                         \
    if (t == BT - 1) {                                                        \
        _Pragma("unroll")                                                     \
        for (int c = EPT - 2; c < EPT; ++c) {                                 \
            const float s1_ = Q[c + 1] + Q[c + 3];                            \
            const float s2_ = Q[c]     + Q[c + 4];                            \
            float cv_ = fmaf(0.01f, s1_, Q[c + 2]);                           \
            cv_ = fmaf(0.0025f, s2_, cv_);                                    \
            const float sel_ = (XC[c] > 0.f) ? wf[c] : -wf[c];                \
            const double de_ = (c == EPT - 1) ? DE0 : DE1;                    \
            cD_ += de_ * (double)(cv_ * sel_);                                \
            cT_ += de_ * (double)(cv_ * fabsf(sel_));                         \
        }                                                                     \
    }                                                                         \
    double accD_ = ((double)Dv_[0] + (double)Dv_[1])                          \
                 + ((double)Dv_[2] + (double)Dv_[3]);                         \
    float  accT_ = (Tv_[0] + Tv_[1]) + (Tv_[2] + Tv_[3]);                     \
    _Pragma("unroll")                                                         \
    for (int off = 32; off; off >>= 1) {                                      \
        accD_ += __shfl_down(accD_, off);                                     \
        accT_ += __shfl_down(accT_, off);                                     \
    }                                                                         \
    if (lane == 0)   { redD[R][wid] = accD_; redT[R][wid] = accT_; }          \
    if (t == 0)      { corrd[R][0] = cD_; corrd[R][1] = cT_; }                \
    if (t == BT - 1) { corrd[R][2] = cD_; corrd[R][3] = cT_; }                \
    asm volatile("s_waitcnt lgkmcnt(0)" ::: "memory");                        \
    __builtin_amdgcn_s_barrier();                                             \
    if (t == 0) {                                                             \
        double D_ = 0.0, T_ = 0.0;                                            \
        _Pragma("unroll")                                                     \
        for (int i = 0; i < 8; ++i) { D_ += redD[R][i]; T_ += (double)redT[R][i]; } \
        const double E_MID = 1.0 + 2.0 * (double)0.01f + 2.0 * (double)0.0025f;\
        D_ = D_ * E_MID + (corrd[R][0] + corrd[R][2]);                        \
        T_ = T_ * E_MID + (corrd[R][1] + corrd[R][3]);                        \
        const double Kd = (10.0 / 255.0) * (YB_LOSS_D * MZM_LOSS_D) / (double)wnorm;\
        const double ps = (T_ + D_) * 0.5 * Kd * MRR_LOSS_D;                  \
        const double ns = (T_ - D_) * 0.5 * Kd * MRR_LOSS_D;                  \
        const float thermal_f = 3.3135576e-12f;                               \
        const float shot_f    = 3.204353268e-9f;                              \
        double tp_ = ps + 1e-12 + (double)(vntp_ * thermal_f);                \
        tp_ *= (double)(1.0f + vnsp_ * shot_f);                               \
        double tn_ = ns + 1e-12 + (double)(vntn_ * thermal_f);                \
        tn_ *= (double)(1.0f + vnsn_ * shot_f);                               \
        const double cur = tp_ - tn_;                                         \
        double v_ = fabs(cur * 100.0);                                        \
        v_ = fmin(v_, 1.0);                                                   \
        const double va_  = rint(v_ * 255.0) * (1.0 / 255.0);                 \
        const double sgn_ = (cur >= 0.0) ? 1.0 : -1.0;                        \
        const double scale_ = (double)wnorm /                                 \
            (10.0 * 100.0 * MRR_LOSS_D * YB_LOSS_D * MZM_LOSS_D);             \
        out[row_] = (float)(va_ * sgn_ * scale_ * (double)inorm_);            \
    }                                                                         \
} while (0)

__global__ __launch_bounds__(BT, 4)
void odp_main(const float* __restrict__ x, const float* __restrict__ w,
              const float* __restrict__ ntp, const float* __restrict__ nsp,
              const float* __restrict__ ntn, const float* __restrict__ nsn,
              float* __restrict__ out)
{
    __shared__ float  redX[ROWS][8];
    __shared__ float  redW[8];
    __shared__ float  redT[ROWS][8];
    __shared__ double redD[ROWS][8];
    __shared__ double corrd[ROWS][4];

    const int t    = threadIdx.x;
    const int lane = t & 63;
    const int wid  = t >> 6;
    const int r0   = blockIdx.x * ROWS;

    const double DE0 = -((double)0.01f + (double)0.0025f);  // i = 0, N-1
    const double DE1 = -((double)0.0025f);                  // i = 1, N-2

    // ---- block prologue: w once (shared by all 8 rows) + row 0 of x ----
    const float4* __restrict__ w4 = (const float4*)w;
    float wf[EPT];
    float mw = 0.f;
#pragma unroll
    for (int j = 0; j < 4; ++j) {
        const float4 wv = w4[t * 4 + j];
        wf[4*j+0]=wv.x; wf[4*j+1]=wv.y; wf[4*j+2]=wv.z; wf[4*j+3]=wv.w;
        mw = fmaxf(mw, fmaxf(fmaxf(fabsf(wv.x), fabsf(wv.y)),
                             fmaxf(fabsf(wv.z), fabsf(wv.w))));
    }
#pragma unroll
    for (int off = 32; off; off >>= 1)
        mw = fmaxf(mw, __shfl_down(mw, off));

    float xA[EPT], xB[EPT];
    float2 hLA, hRA, hLB, hRB;
    LOADX(xA, hLA, hRA, r0);

    float wnorm = 1.f;   // set in row 0

    // ---- 8 rows, software-pipelined: prefetch r+1, compute r ----
    ROW_BODY(0, xA, hLA, hRA, LOADX(xB, hLB, hRB, r0 + 1));
    ROW_BODY(1, xB, hLB, hRB, LOADX(xA, hLA, hRA, r0 + 2));
    ROW_BODY(2, xA, hLA, hRA, LOADX(xB, hLB, hRB, r0 + 3));
    ROW_BODY(3, xB, hLB, hRB, LOADX(xA, hLA, hRA, r0 + 4));
    ROW_BODY(4, xA, hLA, hRA, LOADX(xB, hLB, hRB, r0 + 5));
    ROW_BODY(5, xB, hLB, hRB, LOADX(xA, hLA, hRA, r0 + 6));
    ROW_BODY(6, xA, hLA, hRA, LOADX(xB, hLB, hRB, r0 + 7));
    ROW_BODY(7, xB, hLB, hRB, ((void)0));
}

extern "C" void kernel_launch(void* const* d_in, const int* in_sizes, int n_in,
                              void* d_out, int out_size, void* d_ws, size_t ws_size,
                              hipStream_t stream) {
    const float* x   = (const float*)d_in[0];
    const float* w   = (const float*)d_in[1];
    const float* ntp = (const float*)d_in[2];
    const float* nsp = (const float*)d_in[3];
    const float* ntn = (const float*)d_in[4];
    const float* nsn = (const float*)d_in[5];
    float* out = (float*)d_out;
    const int nblocks = (out_size + ROWS - 1) / ROWS;
    odp_main<<<dim3(nblocks), dim3(BT), 0, stream>>>(x, w, ntp, nsp, ntn, nsn, out);
}